// Round 5
// baseline (149.308 us; speedup 1.0000x reference)
//
#include <hip/hip_runtime.h>
#include <stdint.h>

// FC tensor product as on-the-fly-A GEMMs, f16, MFMA f32_16x16x32_f16.
// A[r,(u,v)] = a[r,u]*b[r,v]: b octets in registers all phase (u-independent),
// a octets in registers per superstep, W pairs (K=64) stream through 4 LDS
// pair-slots with counted vmcnt, and W octets for macro t+1 are prefetched
// into registers (bwA/bwB) during macro t so MFMAs never wait on LDS latency.

typedef _Float16 f16;
typedef f16 f16x8 __attribute__((ext_vector_type(8)));
typedef float f32x4 __attribute__((ext_vector_type(4)));
typedef int i32x4 __attribute__((ext_vector_type(4)));

#define OFF_W000 0u
#define OFF_W110 2097152u
#define OFF_W011 2621440u
#define OFF_W101 3145728u
#define OFF_W111 3670016u        // size 262144 (64*64*64)
#define OFF_XS1  3932160u
#define OFF_XS2  4980736u
#define OFF_XV1  6029312u
#define OFF_XV2  7602176u
#define OFF_S0A  9175040u
#define OFF_S0B  10223616u
#define OFF_S1O  13369344u
#define WS_ELEMS 14942208u

#define SC_0E 0.006987712429686843f
#define SC_1O 0.0078125f
#define SC_1E 0.011048543456039806f

// ---------------- pre-kernel: retile everything to f16 ----------------
// total threads = 9175040 = 35840 blocks * 256 (exact; every branch bound exact)
__global__ void tile_all_k(const float* __restrict__ w000, const float* __restrict__ w011,
                           const float* __restrict__ w101, const float* __restrict__ w110,
                           const float* __restrict__ w111, const float* __restrict__ x1,
                           const float* __restrict__ x2, f16* __restrict__ ws)
{
  unsigned tid = blockIdx.x*256u + threadIdx.x;
  if (tid < 2097152u) {  // W000t [vh][u][p][q][n128][8]
    unsigned e=tid&7u, n=(tid>>3)&127u, q=(tid>>10)&3u, p=(tid>>12)&1u, u=(tid>>13)&127u, vh=(tid>>20)&1u;
    unsigned v = vh*64u + p*32u + q*8u + e;
    ws[OFF_W000+tid] = (f16)w000[u*16384u + v*128u + n];
    return;
  }
  tid -= 2097152u;
  if (tid < 524288u) {   // W110t [u64][p][q][n128][8], fold 1/sqrt3
    unsigned e=tid&7u, n=(tid>>3)&127u, q=(tid>>10)&3u, p=(tid>>12)&1u, u=tid>>13;
    unsigned v = p*32u + q*8u + e;
    ws[OFF_W110+tid] = (f16)(w110[u*8192u + v*128u + n] * 0.5773502691896258f);
    return;
  }
  tid -= 524288u;
  if (tid < 524288u) {   // W011t [u128][p][q][n64][8]
    unsigned e=tid&7u, n=(tid>>3)&63u, q=(tid>>9)&3u, p=(tid>>11)&1u, u=tid>>12;
    unsigned v = p*32u + q*8u + e;
    ws[OFF_W011+tid] = (f16)w011[u*4096u + v*64u + n];
    return;
  }
  tid -= 524288u;
  if (tid < 524288u) {   // W101t [u=s2 128][p][q][n64][8]  (transposed)
    unsigned e=tid&7u, n=(tid>>3)&63u, q=(tid>>9)&3u, p=(tid>>11)&1u, u=tid>>12;
    unsigned v = p*32u + q*8u + e;   // v1 index
    ws[OFF_W101+tid] = (f16)w101[v*8192u + u*64u + n];
    return;
  }
  tid -= 524288u;
  if (tid < 262144u) {   // W111t [u64][p][q][n64][8]  (exact size 64*64*64)
    unsigned e=tid&7u, n=(tid>>3)&63u, q=(tid>>9)&3u, p=(tid>>11)&1u, u=tid>>12;
    unsigned v = p*32u + q*8u + e;
    ws[OFF_W111+tid] = (f16)w111[u*4096u + v*64u + n];
    return;
  }
  tid -= 262144u;
  if (tid < 1048576u) {  // xs1 [rt][uo16][r128][8]
    unsigned e=tid&7u, r=(tid>>3)&127u, uo=(tid>>10)&15u, rt=tid>>14;
    ws[OFF_XS1+tid] = (f16)x1[(rt*128u+r)*320u + uo*8u + e];
    return;
  }
  tid -= 1048576u;
  if (tid < 1572864u) {  // xv1 [rt][i3][ov8][r128][8]
    unsigned e=tid&7u, r=(tid>>3)&127u, ov=(tid>>10)&7u, rest=tid>>13;
    unsigned i=rest%3u, rt=rest/3u;
    ws[OFF_XV1+tid] = (f16)x1[(rt*128u+r)*320u + 128u + (ov*8u+e)*3u + i];
    return;
  }
  tid -= 1572864u;
  if (tid < 1048576u) {  // xs2
    unsigned e=tid&7u, r=(tid>>3)&127u, uo=(tid>>10)&15u, rt=tid>>14;
    ws[OFF_XS2+tid] = (f16)x2[(rt*128u+r)*320u + uo*8u + e];
    return;
  }
  tid -= 1048576u;
  {                      // xv2 (exactly 1572864 remain)
    unsigned e=tid&7u, r=(tid>>3)&127u, ov=(tid>>10)&7u, rest=tid>>13;
    unsigned i=rest%3u, rt=rest/3u;
    ws[OFF_XV2+tid] = (f16)x2[(rt*128u+r)*320u + 128u + (ov*8u+e)*3u + i];
  }
}

// ---------------- main kernel ----------------
#define GLD16(g,l) __builtin_amdgcn_global_load_lds( \
    (const __attribute__((address_space(1))) unsigned int*)(g), \
    (__attribute__((address_space(3))) unsigned int*)(l), 16, 0, 0)

#define WAITV(n) asm volatile("s_waitcnt vmcnt(" #n ")" ::: "memory")

// One phase: acc += A*W.  SS supersteps; each superstep = 8 pair-macros;
// pair-macro = 2 K-tiles of 32 (u = macro index, both v-parities).
// Stage pipeline (steady state, per wave): entering macro t the vmcnt FIFO is
// [P(t+1), P(t+2)]; top-wait drains P(t+1); body prefetches slot (t+1)&3 into
// the alternate bw reg buffer and issues P(t+3). MFMAs read only registers.
template<int N, bool NEG, int SS>   // N = W tile col count (128 or 64)
__device__ __forceinline__ void run_phase(const f16* __restrict__ Wt,
    const f16* __restrict__ aW, const f16* __restrict__ bW, int bRow, int h,
    f16* sW, f16* sAw, f32x4 (&acc)[4][4])
{
  constexpr int S     = N/64;      // GLD16 issues per wave per tile
  constexpr int TILEB = N*64;      // tile bytes
  constexpr int PAIRB = 2*TILEB;   // pair bytes
  constexpr int TILEE = N*32;      // tile f16 elems
  constexpr int PAIRE = 2*TILEE;
  constexpr int M     = SS*8;      // pair-macros
  const int lane = threadIdx.x & 63, wid = threadIdx.x >> 6;
  const int q = lane >> 4, r15 = lane & 15;

  WAITV(0);   // clear outstanding vmem from prior phase for exact counting

  // b octets for the whole phase -> registers (u-independent)
  f16x8 br[4][2];
#pragma unroll
  for (int mt=0; mt<4; ++mt)
#pragma unroll
    for (int o=0; o<2; ++o)
      br[mt][o] = *(const f16x8*)(bW + (o*4+q)*1024 + (bRow + mt*16 + r15)*8);
#pragma unroll
  for (int mt=0; mt<4; ++mt)
#pragma unroll
    for (int o=0; o<2; ++o) {      // force loads complete now (vmcnt -> 0)
      i32x4 tmp = __builtin_bit_cast(i32x4, br[mt][o]);
      asm volatile("" :: "v"(tmp));
    }

  const int wchunk = wid*S*1024;
  auto stPair = [&](int p, int slot){
    const char* s = (const char*)Wt + (size_t)p*PAIRB + wchunk;
    char* d = (char*)sW + slot*PAIRB + wchunk;
#pragma unroll
    for (int tt=0; tt<2; ++tt)
#pragma unroll
      for (int c=0; c<S; ++c)
        GLD16(s + tt*TILEB + c*1024 + lane*16, d + tt*TILEB + c*1024);
  };
  auto stA = [&](int ss2){   // 1KB a-chunk for superstep ss2 into per-wave slot
    GLD16((const char*)(aW + ss2*1024) + lane*16, (char*)sAw + (ss2&1)*1024);
  };

  // prologue: 3 pairs in flight + a-chunk 0; drain stA+P(0), keep P(1),P(2)
  stA(0); stPair(0,0); stPair(1,1); stPair(2,2);
  if constexpr (S==1) WAITV(4); else WAITV(8);
  __builtin_amdgcn_s_barrier();
  __builtin_amdgcn_sched_barrier(0);

  f16x8 bwA[8], bwB[8];      // W octets, double-buffered by macro parity
  auto ldBW = [&](f16x8 (&dst)[8], int slot){
#pragma unroll
    for (int tt=0; tt<2; ++tt)
#pragma unroll
      for (int nt=0; nt<4; ++nt)
        dst[tt*4+nt] = *(const f16x8*)(sW + slot*PAIRE + tt*TILEE
                                       + (q*N + h*64 + nt*16 + r15)*8);
  };
  ldBW(bwA, 0);              // macro 0's octets (slot 0 resident)

  f16x8 aR[4];

#pragma unroll 1
  for (int ss = 0; ss < SS; ++ss) {
#pragma unroll
    for (int k = 0; k < 8; ++k) {
      const int t = ss*8 + k;
      // ---- top wait: drain P(t+1) (+stA when pending); keep P(t+2) in flight
      if (t + 2 < M) { if constexpr (S==1) WAITV(2); else WAITV(4); }
      else           WAITV(0);
      __builtin_amdgcn_s_barrier();
      __builtin_amdgcn_sched_barrier(0);
      // ---- issues (FIFO order: stA before stPair)
      if (k == 6 && ss+1 < SS) stA(ss+1);
      if (t + 3 < M) stPair(t+3, (t+3)&3);
      // ---- a octets for this superstep (own-wave chunk, vmcnt-drained)
      if (k == 0) {
#pragma unroll
        for (int mt=0; mt<4; ++mt)
          aR[mt] = *(const f16x8*)(sAw + (ss&1)*512 + (mt*16+r15)*8);
      }
      // ---- prefetch macro t+1's W octets into the alternate reg buffer
      if (t + 1 < M) {
        if (k & 1) ldBW(bwA, (t+1)&3); else ldBW(bwB, (t+1)&3);
      }
      const f16x8 (&bw)[8] = (k & 1) ? bwB : bwA;
      // ---- A fragments + 32 MFMA (registers only)
      __builtin_amdgcn_s_setprio(1);
#pragma unroll
      for (int tt=0; tt<2; ++tt) {
        f16x8 af[4];
#pragma unroll
        for (int mt=0; mt<4; ++mt) {
          f16 av = aR[mt][k];
          if constexpr (NEG) av = -av;
          af[mt] = av * br[mt][tt];
        }
#pragma unroll
        for (int nt=0; nt<4; ++nt)
#pragma unroll
          for (int mt=0; mt<4; ++mt)
            acc[mt][nt] = __builtin_amdgcn_mfma_f32_16x16x32_f16(af[mt], bw[tt*4+nt], acc[mt][nt], 0,0,0);
      }
      __builtin_amdgcn_s_setprio(0);
    }
  }
  __builtin_amdgcn_s_barrier();     // protect sW/sA before next phase / epilogue
  __builtin_amdgcn_sched_barrier(0);
}

__global__ __launch_bounds__(256, 2)
void tp_main(f16* __restrict__ ws, float* __restrict__ out)
{
  __shared__ f16 smem[36864];       // 72KB: sW 4 pair-slots x 16KB | per-wave a 2x1KB
  f16* sW = smem;
  const int lane = threadIdx.x & 63, wid = threadIdx.x >> 6;
  f16* sAw = smem + 32768 + wid*1024;
  const int q = lane >> 4, r15 = lane & 15;

  f32x4 acc[4][4];
#pragma unroll
  for (int a=0;a<4;++a)
#pragma unroll
    for (int b=0;b<4;++b) acc[a][b] = (f32x4){0.f,0.f,0.f,0.f};

  const int bid = blockIdx.x;

  if (bid < 128) {          // ---- J0a: w000, v-half vh. waves: 2 rgrp x 2 h
    const int rt = bid >> 1, vh = bid & 1;
    const int rgrp = wid >> 1, h = wid & 1;
    const f16* aW = ws + OFF_XS1 + rt*16384 + rgrp*512;
    const f16* bW = ws + OFF_XS2 + rt*16384 + vh*8192;
    run_phase<128,false,16>(ws + OFF_W000 + vh*1048576u, aW, bW, rgrp*64, h, sW, sAw, acc);
    const int rowb = rt*128 + rgrp*64;
    if (vh == 0) {
#pragma unroll
      for (int mt=0;mt<4;++mt)
#pragma unroll
        for (int nt=0;nt<4;++nt)
#pragma unroll
          for (int rg=0;rg<4;++rg)
            out[(rowb+mt*16+q*4+rg)*512 + h*64+nt*16+r15] = SC_0E*acc[mt][nt][rg];
    } else {
      f16* slab = ws + OFF_S0A;
#pragma unroll
      for (int mt=0;mt<4;++mt)
#pragma unroll
        for (int nt=0;nt<4;++nt)
#pragma unroll
          for (int rg=0;rg<4;++rg)
            slab[(rowb+mt*16+q*4+rg)*128 + h*64+nt*16+r15] = (f16)(SC_0E*acc[mt][nt][rg]);
    }
  } else if (bid < 224) {   // ---- J1o-a: w011 (a=s1, b=v2_i), 4 row-groups
    const int id = bid-128, i = id%3, rt = id/3;
    const int rgrp = wid, ro = rgrp & 1, sub = rgrp >> 1;
    const int rtt = rt*2 + sub;
    const f16* aW = ws + OFF_XS1 + rtt*16384 + ro*512;
    const f16* bW = ws + OFF_XV2 + (rtt*3+i)*8192;
    run_phase<64,false,16>(ws + OFF_W011, aW, bW, ro*64, 0, sW, sAw, acc);
    const int rowb = rt*256 + rgrp*64;
#pragma unroll
    for (int mt=0;mt<4;++mt)
#pragma unroll
      for (int nt=0;nt<4;++nt)
#pragma unroll
        for (int rg=0;rg<4;++rg)
          out[(rowb+mt*16+q*4+rg)*512 + 128 + 3*(nt*16+r15) + i] = SC_1O*acc[mt][nt][rg];
  } else if (bid < 320) {   // ---- J1o-b: w101 (a=s2, b=v1_i) -> f16 slab
    const int id = bid-224, i = id%3, rt = id/3;
    const int rgrp = wid, ro = rgrp & 1, sub = rgrp >> 1;
    const int rtt = rt*2 + sub;
    const f16* aW = ws + OFF_XS2 + rtt*16384 + ro*512;
    const f16* bW = ws + OFF_XV1 + (rtt*3+i)*8192;
    run_phase<64,false,16>(ws + OFF_W101, aW, bW, ro*64, 0, sW, sAw, acc);
    const int rowb = rt*256 + rgrp*64;
    f16* slab = ws + OFF_S1O;
#pragma unroll
    for (int mt=0;mt<4;++mt)
#pragma unroll
      for (int nt=0;nt<4;++nt)
#pragma unroll
        for (int rg=0;rg<4;++rg)
          slab[(rowb+mt*16+q*4+rg)*192 + 3*(nt*16+r15) + i] = (f16)(SC_1O*acc[mt][nt][rg]);
  } else if (bid < 416) {   // ---- J1e: w111 cross component kk (two signed terms)
    const int id = bid-320, kk = id%3, rt = id/3;
    int i = kk+1; if (i>2) i-=3;
    int j = kk+2; if (j>2) j-=3;
    const int rgrp = wid, ro = rgrp & 1, sub = rgrp >> 1;
    const int rtt = rt*2 + sub;
    run_phase<64,false,8>(ws + OFF_W111,
        ws + OFF_XV1 + (rtt*3+i)*8192 + ro*512, ws + OFF_XV2 + (rtt*3+j)*8192,
        ro*64, 0, sW, sAw, acc);
    run_phase<64,true,8>(ws + OFF_W111,
        ws + OFF_XV1 + (rtt*3+j)*8192 + ro*512, ws + OFF_XV2 + (rtt*3+i)*8192,
        ro*64, 0, sW, sAw, acc);
    const int rowb = rt*256 + rgrp*64;
#pragma unroll
    for (int mt=0;mt<4;++mt)
#pragma unroll
      for (int nt=0;nt<4;++nt)
#pragma unroll
        for (int rg=0;rg<4;++rg)
          out[(rowb+mt*16+q*4+rg)*512 + 320 + 3*(nt*16+r15) + kk] = SC_1E*acc[mt][nt][rg];
  } else {                  // ---- J0b: w110' (v1_i x v2_i), two rt per block
    const int id = bid-416, i = id%3, rp = id/3;
    const int rgrp = wid >> 1, h = wid & 1;
#pragma unroll 1
    for (int hh = 0; hh < 2; ++hh) {
      const int rt = rp*2 + hh;
      const f16* aW = ws + OFF_XV1 + (rt*3+i)*8192 + rgrp*512;
      const f16* bW = ws + OFF_XV2 + (rt*3+i)*8192;
      run_phase<128,false,8>(ws + OFF_W110, aW, bW, rgrp*64, h, sW, sAw, acc);
      const int rowb = rt*128 + rgrp*64;
      f16* slab = ws + OFF_S0B + (unsigned)i*1048576u;
#pragma unroll
      for (int mt=0;mt<4;++mt)
#pragma unroll
        for (int nt=0;nt<4;++nt)
#pragma unroll
          for (int rg=0;rg<4;++rg) {
            slab[(rowb+mt*16+q*4+rg)*128 + h*64+nt*16+r15] = (f16)(SC_0E*acc[mt][nt][rg]);
            acc[mt][nt][rg] = 0.f;
          }
    }
  }
}

// ---------------- epilogue: fold f16 partial slabs into out ----------------
__global__ void ep_add(const f16* __restrict__ ws, float* __restrict__ out)
{
  unsigned tid = blockIdx.x*256u + threadIdx.x;
  if (tid < 1048576u) {
    unsigned r = tid>>7, c = tid&127u;
    float s = (float)ws[OFF_S0A+tid] + (float)ws[OFF_S0B+tid]
            + (float)ws[OFF_S0B+1048576u+tid] + (float)ws[OFF_S0B+2097152u+tid];
    out[r*512u+c] += s;
  } else {
    unsigned t2 = tid - 1048576u;
    unsigned r = t2/192u, c = t2 - r*192u;
    out[r*512u+128u+c] += (float)ws[OFF_S1O+t2];
  }
}

extern "C" void kernel_launch(void* const* d_in, const int* in_sizes, int n_in,
                              void* d_out, int out_size, void* d_ws, size_t ws_size,
                              hipStream_t stream)
{
  const float* x1   = (const float*)d_in[0];
  const float* x2   = (const float*)d_in[1];
  const float* w000 = (const float*)d_in[2];
  const float* w011 = (const float*)d_in[3];
  const float* w101 = (const float*)d_in[4];
  const float* w110 = (const float*)d_in[5];
  const float* w111 = (const float*)d_in[6];
  float* out = (float*)d_out;
  f16* ws   = (f16*)d_ws;

  if (ws_size < (size_t)WS_ELEMS * 2) return;   // ~29.9 MB scratch

  tile_all_k<<<35840, 256, 0, stream>>>(w000, w011, w101, w110, w111, x1, x2, ws);
  tp_main<<<512, 256, 0, stream>>>(ws, out);
  ep_add<<<10240, 256, 0, stream>>>(ws, out);
}